// Round 17
// baseline (65.050 us; speedup 1.0000x reference)
//
#include <hip/hip_runtime.h>
#include <hip/hip_bf16.h>

#define Bb 8
#define Nn 1024
#define Hh 12
#define C3 2304
#define KK_E 0.1803368801f   // (1/8) * log2(e)
#define NQB 128              // queries per block (4 waves x 32)
#define KVBLK 64
#define NT 29
#define NQT (Nn / NQB)       // 8
#define NKT (Nn / KVBLK)     // 16
#define NBLK (Bb * Hh * NQT) // 768
#define TILE_ELEMS 4096      // 64x64 bf16 tile

typedef short bf16x8 __attribute__((ext_vector_type(8)));
typedef float f32x16 __attribute__((ext_vector_type(16)));
typedef unsigned v2u __attribute__((ext_vector_type(2)));
typedef unsigned short u16t;

__device__ __forceinline__ float b2f(u16t v) {
    union { unsigned u; float f; } x; x.u = ((unsigned)v) << 16; return x.f;
}
__device__ __forceinline__ u16t f2b(float f) {
    union { float f; unsigned u; } x; x.f = f;
    unsigned r = x.u + 0x7fffu + ((x.u >> 16) & 1u);
    return (u16t)(r >> 16);
}
// single-instruction packed f32->bf16 (T12): dst.lo=bf16(a), dst.hi=bf16(b)
__device__ __forceinline__ unsigned pk2a(float a, float b) {
    unsigned r;
    asm("v_cvt_pk_bf16_f32 %0, %1, %2" : "=v"(r) : "v"(a), "v"(b));
    return r;
}

// ---------------- pass 1: fp32 -> bf16 in FRAG-LINEAR tile layout ----------------
// K tile (8KB): u16 idx = (key&31)*8 + (key>>5)*256 + ((d>>3)&1)*512 + (d>>4)*1024 + (d&7)
// V tile (8KB): u16 idx = (d&31)*8 + ((d>>5)&1)*256 + ((key>>3)&1)*512 + (key>>4)*1024 + (key&7)
// -> every MFMA fragment is 64 consecutive 16B chunks (one coalesced dwordx4 per lane)
__global__ __launch_bounds__(256) void preconv_kernel(
        const float* __restrict__ x, u16t* __restrict__ wsK, u16t* __restrict__ wsV) {
    __shared__ __align__(16) u16t Vt[TILE_ELEMS];
    const int bid = blockIdx.x;                 // ((b*H + h)*NKT + kt)
    const int kt = bid % NKT;
    const int h  = (bid / NKT) % Hh;
    const int b  = bid / (NKT * Hh);
    const int tid = threadIdx.x;
    const float* xb = x + (size_t)b * Nn * C3 + (size_t)kt * KVBLK * C3 + 768 + h * 64;
    u16t* Kdst = wsK + (size_t)bid * TILE_ELEMS;
    u16t* Vdst = wsV + (size_t)bid * TILE_ELEMS;

    #pragma unroll
    for (int rep = 0; rep < 4; ++rep) {
        int idx = tid + rep * 256;
        int m = idx >> 4;               // key 0..63
        int d0 = (idx & 15) * 4;        // d0 in {0,4,...,60}
        const float* src = &xb[(size_t)m * C3 + d0];
        float4 k4 = *(const float4*)src;
        uint2 kp;
        kp.x = pk2a(k4.x, k4.y);
        kp.y = pk2a(k4.z, k4.w);
        int ko = (m & 31) * 8 + (m >> 5) * 256 + ((d0 >> 3) & 1) * 512
               + (d0 >> 4) * 1024 + (d0 & 7);
        *(uint2*)&Kdst[ko] = kp;        // direct global, 8B aligned
        float4 v4 = *(const float4*)(src + 768);
        int vb = ((m >> 3) & 1) * 512 + (m >> 4) * 1024 + (m & 7);
        Vt[((d0 + 0) & 31) * 8 + (((d0 + 0) >> 5) & 1) * 256 + vb] = f2b(v4.x);
        Vt[((d0 + 1) & 31) * 8 + (((d0 + 1) >> 5) & 1) * 256 + vb] = f2b(v4.y);
        Vt[((d0 + 2) & 31) * 8 + (((d0 + 2) >> 5) & 1) * 256 + vb] = f2b(v4.z);
        Vt[((d0 + 3) & 31) * 8 + (((d0 + 3) >> 5) & 1) * 256 + vb] = f2b(v4.w);
    }
    __syncthreads();
    // tile already frag-linear in LDS: plain linear copy-out
    const float4* s = (const float4*)Vt;
    float4* d = (float4*)Vdst;
    d[tid] = s[tid];
    d[tid + 256] = s[tid + 256];
}

// ---------------- pass 2: attention — zero barriers, K/V register-resident ------
// r13 structure (62.5us baseline) + QK chain split: two independent 2-chains
// (s0, s1) merged with 16 adds — halves the exposed dependent-MFMA latency.
// s1 is a SHORT live range (4 MFMAs + merge) — unlike r14/r15's cross-fin sB,
// the allocator can keep it clean.
// __launch_bounds__(256,3): budget 170 — the only clean budget for this body.
// CLOSED AXES (do not revisit): occupancy>3waves/SIMD (r8-r11); cross-step
// pipeline state (r12/r14/r15 -> spill).
__global__ __launch_bounds__(256, 3) void attn_kernel(
        const float* __restrict__ x,
        const float* __restrict__ tk,
        const float* __restrict__ tv,
        const u16t* __restrict__ wsK,
        const u16t* __restrict__ wsV,
        float* __restrict__ out) {
    __shared__ __align__(16) char smem[16384];

    const int tid = threadIdx.x;
    const int work = (blockIdx.x & 7) * (NBLK / 8) + (blockIdx.x >> 3);
    const int qt = work % NQT;
    const int h  = (work / NQT) % Hh;
    const int b  = work / (NQT * Hh);
    const int lane = tid & 63;
    const int w = tid >> 6;
    const int lq = lane & 31;
    const int hi = lane >> 5;
    const int q0 = qt * NQB;
    const int qw0 = q0 + w * 32;

    char* slab   = smem + w * 4096;
    u16t* wdiagw = (u16t*)slab;              // [32][27] bf16
    u16t* qrelw  = (u16t*)(slab + 1792);     // [32][29] bf16 -> W[32][32] after loop

    const u16t* Kbase = wsK + (size_t)((b * Hh + h) * NKT) * TILE_ELEMS;
    const u16t* Vbase = wsV + (size_t)((b * Hh + h) * NKT) * TILE_ELEMS;
    const int lofs = lq * 8 + hi * 512;      // per-lane u16 offset inside a tile

    // ---- tile-0 K/V fragments straight into registers (coalesced dwordx4) ----
    bf16x8 kfr[2][4];   // [kb][slot]
    bf16x8 vfr[4][2];   // [kbj][db]
    {
        const u16t* Kt0 = Kbase + lofs;
        const u16t* Vt0 = Vbase + lofs;
        #pragma unroll
        for (int kb = 0; kb < 2; ++kb)
            #pragma unroll
            for (int slot = 0; slot < 4; ++slot)
                kfr[kb][slot] = *(const bf16x8*)&Kt0[kb * 256 + slot * 1024];
        #pragma unroll
        for (int kbj = 0; kbj < 4; ++kbj)
            #pragma unroll
            for (int db = 0; db < 2; ++db)
                vfr[kbj][db] = *(const bf16x8*)&Vt0[db * 256 + kbj * 1024];
    }

    // ---- Q fragments direct from global, pre-scaled by KK_E ----
    const float* xq = x + (size_t)b * Nn * C3 + (size_t)(qw0 + lq) * C3 + h * 64;
    bf16x8 qB[4];
    #pragma unroll
    for (int slot = 0; slot < 4; ++slot) {
        float4 a4 = *(const float4*)&xq[slot * 16 + hi * 8];
        float4 b4 = *(const float4*)&xq[slot * 16 + hi * 8 + 4];
        union { bf16x8 v; unsigned u[4]; } pk;
        pk.u[0] = pk2a(a4.x * KK_E, a4.y * KK_E);
        pk.u[1] = pk2a(a4.z * KK_E, a4.w * KK_E);
        pk.u[2] = pk2a(b4.x * KK_E, b4.y * KK_E);
        pk.u[3] = pk2a(b4.z * KK_E, b4.w * KK_E);
        qB[slot] = pk.v;
    }

    // ---- qrel[q][t] = (KK_E*Q[q,:]).tk[t,:] via 4 MFMAs: D[q=crow(reg,hi)][t=lq] ----
    {
        const int tc = lq > 28 ? 28 : lq;
        f32x16 qr = {};
        #pragma unroll
        for (int slot = 0; slot < 4; ++slot) {
            const float* tp = &tk[tc * 64 + slot * 16 + hi * 8];
            float4 a4 = *(const float4*)tp;
            float4 b4 = *(const float4*)(tp + 4);
            union { bf16x8 v; unsigned u[4]; } pk;
            pk.u[0] = pk2a(a4.x, a4.y); pk.u[1] = pk2a(a4.z, a4.w);
            pk.u[2] = pk2a(b4.x, b4.y); pk.u[3] = pk2a(b4.z, b4.w);
            qr = __builtin_amdgcn_mfma_f32_32x32x16_bf16(qB[slot], pk.v, qr, 0, 0, 0);
        }
        if (lq <= 28) {
            #pragma unroll
            for (int reg = 0; reg < 16; ++reg) {
                int qrow = (reg & 3) + 8 * (reg >> 2) + 4 * hi;
                qrelw[qrow * NT + lq] = f2b(qr[reg]);
            }
        }
    }
    // zero wdiag (wave-private; compiler orders LDS ops within the wave)
    for (int i = lane; i < 432; i += 64) ((unsigned*)wdiagw)[i] = 0u;

    const float qb0  = b2f(qrelw[lq * NT + 0]);    // already scaled
    const float qb28 = b2f(qrelw[lq * NT + 28]);

    f32x16 of[2] = {};
    float lowA = 0.f, highA = 0.f;

    for (int kt = 0; kt < NKT; ++kt) {
        const int key00 = kt * KVBLK;
        const bool more = (kt + 1 < NKT);
        const u16t* Ktn = Kbase + (size_t)(kt + 1) * TILE_ELEMS + lofs;
        const u16t* Vtn = Vbase + (size_t)(kt + 1) * TILE_ELEMS + lofs;

        #pragma unroll
        for (int kb = 0; kb < 2; ++kb) {
            const int kbase = key00 + kb * 32;
            const bool flo = (kbase + 31 - qw0 <= -14);
            const bool fhi = (kbase - (qw0 + 31) >= 14);
            const float binit = flo ? qb0 : (fhi ? qb28 : 0.f);
            // QK as two independent 2-chains (halved dependent-MFMA latency);
            // s1 is transient (dies at the merge) — short live range, no spill.
            f32x16 s, s1;
            #pragma unroll
            for (int r = 0; r < 16; ++r) { s[r] = binit; s1[r] = 0.f; }
            __builtin_amdgcn_s_setprio(1);
            s  = __builtin_amdgcn_mfma_f32_32x32x16_bf16(kfr[kb][0], qB[0], s,  0, 0, 0);
            s1 = __builtin_amdgcn_mfma_f32_32x32x16_bf16(kfr[kb][2], qB[2], s1, 0, 0, 0);
            s  = __builtin_amdgcn_mfma_f32_32x32x16_bf16(kfr[kb][1], qB[1], s,  0, 0, 0);
            s1 = __builtin_amdgcn_mfma_f32_32x32x16_bf16(kfr[kb][3], qB[3], s1, 0, 0, 0);
            __builtin_amdgcn_s_setprio(0);
            // phase-shifted reload: K(kt+1) for this kb, right after last use
            if (more) {
                #pragma unroll
                for (int slot = 0; slot < 4; ++slot)
                    kfr[kb][slot] = *(const bf16x8*)&Ktn[kb * 256 + slot * 1024];
            }
            #pragma unroll
            for (int r = 0; r < 16; ++r) s[r] += s1[r];   // merge (s1 dies here)
            // lane holds S^T[key = kbase+(r&3)+8*(r>>2)+4*hi][q = qw0+lq] (+bias)
            float e[16];
            if (flo || fhi) {
                #pragma unroll
                for (int r = 0; r < 16; ++r) e[r] = __builtin_amdgcn_exp2f(s[r]);
                float a0 = (e[0]+e[1]) + (e[2]+e[3]);
                float a1 = (e[4]+e[5]) + (e[6]+e[7]);
                float a2 = (e[8]+e[9]) + (e[10]+e[11]);
                float a3 = (e[12]+e[13]) + (e[14]+e[15]);
                float at = (a0+a1) + (a2+a3);
                if (flo) lowA += at; else highA += at;
            } else {
                const int qg = qw0 + lq;
                #pragma unroll
                for (int r = 0; r < 16; ++r) {
                    int key = kbase + (r & 3) + 8 * (r >> 2) + 4 * hi;
                    int delta = key - qg;
                    int t = delta + 14;
                    t = t < 0 ? 0 : (t > 28 ? 28 : t);
                    e[r] = __builtin_amdgcn_exp2f(s[r] + b2f(qrelw[lq * NT + t]));
                    if (delta <= -14)      lowA += e[r];
                    else if (delta >= 14)  highA += e[r];
                    else                   wdiagw[lq * 27 + delta + 13] = f2b(e[r]);
                }
            }
            // T12: cvt_pk + permlane32_swap -> PV B-frags in registers
            unsigned A0 = pk2a(e[0],  e[1]),  B0 = pk2a(e[2],  e[3]);
            unsigned C0 = pk2a(e[4],  e[5]),  D0 = pk2a(e[6],  e[7]);
            unsigned A1 = pk2a(e[8],  e[9]),  B1 = pk2a(e[10], e[11]);
            unsigned C1 = pk2a(e[12], e[13]), D1 = pk2a(e[14], e[15]);
            v2u r0 = __builtin_amdgcn_permlane32_swap(A0, C0, false, false);
            v2u r1 = __builtin_amdgcn_permlane32_swap(B0, D0, false, false);
            v2u r2 = __builtin_amdgcn_permlane32_swap(A1, C1, false, false);
            v2u r3 = __builtin_amdgcn_permlane32_swap(B1, D1, false, false);
            union { bf16x8 v; unsigned u[4]; } pf0, pf1;
            pf0.u[0] = r0[0]; pf0.u[1] = r1[0]; pf0.u[2] = r0[1]; pf0.u[3] = r1[1];
            pf1.u[0] = r2[0]; pf1.u[1] = r3[0]; pf1.u[2] = r2[1]; pf1.u[3] = r3[1];
            __builtin_amdgcn_s_setprio(1);
            #pragma unroll
            for (int db = 0; db < 2; ++db) {
                of[db] = __builtin_amdgcn_mfma_f32_32x32x16_bf16(vfr[kb*2+0][db], pf0.v, of[db], 0, 0, 0);
                of[db] = __builtin_amdgcn_mfma_f32_32x32x16_bf16(vfr[kb*2+1][db], pf1.v, of[db], 0, 0, 0);
            }
            __builtin_amdgcn_s_setprio(0);
            // phase-shifted reload: V(kt+1) for this kb's two key sub-groups
            if (more) {
                #pragma unroll
                for (int j = 0; j < 2; ++j)
                    #pragma unroll
                    for (int db = 0; db < 2; ++db)
                        vfr[kb*2+j][db] = *(const bf16x8*)&Vtn[db * 256 + (kb*2+j) * 1024];
            }
        }
    }

    // ---- per-lane finish: both hi halves get full row sums via one swap ----
    lowA  += __shfl_xor(lowA, 32, 64);
    highA += __shfl_xor(highA, 32, 64);
    float wsum = lowA + highA;
    #pragma unroll
    for (int t = 1; t <= 27; ++t) wsum += b2f(wdiagw[lq * 27 + t - 1]);

    // ---- out2 as a 32x64x29 GEMM: W[q][t] @ tv[t][d], 4 MFMAs into `of` ----
    // W[32][32] bf16 built in the dead qrel slab: [lowA | wdiag(27) | highA | 0,0,0]
    {
        u16t* Wl = qrelw;
        union { u16t s[8]; uint4 v; } h0, h1;
        if (hi == 0) {                       // t = 0..15
            h0.s[0] = f2b(lowA);
            #pragma unroll
            for (int t = 1; t <= 7; ++t)  h0.s[t] = wdiagw[lq * 27 + t - 1];
            #pragma unroll
            for (int t = 8; t <= 15; ++t) h1.s[t - 8] = wdiagw[lq * 27 + t - 1];
        } else {                             // t = 16..31
            #pragma unroll
            for (int t = 16; t <= 23; ++t) h0.s[t - 16] = wdiagw[lq * 27 + t - 1];
            #pragma unroll
            for (int t = 24; t <= 27; ++t) h1.s[t - 24] = wdiagw[lq * 27 + t - 1];
            h1.s[4] = f2b(highA);            // t = 28
            h1.s[5] = 0; h1.s[6] = 0; h1.s[7] = 0;
        }
        *(uint4*)&Wl[lq * 32 + hi * 16]     = h0.v;
        *(uint4*)&Wl[lq * 32 + hi * 16 + 8] = h1.v;
        // B-operand frags (same layout as qB): lane -> W[q=lq][t = slot*16 + hi*8 + j]
        bf16x8 wb0 = *(const bf16x8*)&Wl[lq * 32 + hi * 8];
        bf16x8 wb1 = *(const bf16x8*)&Wl[lq * 32 + 16 + hi * 8];
        // A-operand frags: A[d=lq (+32*dh)][t] = tv[t][d]; t>28 zero-padded
        #pragma unroll
        for (int dh = 0; dh < 2; ++dh) {
            union { bf16x8 v; unsigned u[4]; } a0, a1;
            #pragma unroll
            for (int jj = 0; jj < 4; ++jj) {
                int t0 = hi * 8 + 2 * jj;
                a0.u[jj] = pk2a(tv[t0 * 64 + lq + 32 * dh],
                                tv[(t0 + 1) * 64 + lq + 32 * dh]);
                int t1 = 16 + hi * 8 + 2 * jj;
                float v0 = (t1     <= 28) ? tv[t1 * 64 + lq + 32 * dh]       : 0.f;
                float v1 = (t1 + 1 <= 28) ? tv[(t1 + 1) * 64 + lq + 32 * dh] : 0.f;
                a1.u[jj] = pk2a(v0, v1);
            }
            of[dh] = __builtin_amdgcn_mfma_f32_32x32x16_bf16(a0.v, wb0, of[dh], 0, 0, 0);
            of[dh] = __builtin_amdgcn_mfma_f32_32x32x16_bf16(a1.v, wb1, of[dh], 0, 0, 0);
        }
    }
    const float linv = __builtin_amdgcn_rcpf(wsum);

    // ---- epilogue: out[q][d] = of[d][q] / L[q] (of = PV + rel-V) ----
    {
        float* orow = &out[((size_t)b * Nn + qw0 + lq) * 768 + h * 64];
        #pragma unroll
        for (int db = 0; db < 2; ++db)
            #pragma unroll
            for (int rq = 0; rq < 4; ++rq) {
                int d0 = db * 32 + rq * 8 + hi * 4;
                float4 o4;
                o4.x = of[db][rq * 4 + 0] * linv;
                o4.y = of[db][rq * 4 + 1] * linv;
                o4.z = of[db][rq * 4 + 2] * linv;
                o4.w = of[db][rq * 4 + 3] * linv;
                *(float4*)&orow[d0] = o4;
            }
    }
}

extern "C" void kernel_launch(void* const* d_in, const int* in_sizes, int n_in,
                              void* d_out, int out_size, void* d_ws, size_t ws_size,
                              hipStream_t stream) {
    const float* x  = (const float*)d_in[0];
    const float* tk = (const float*)d_in[1];
    const float* tv = (const float*)d_in[2];
    float* out = (float*)d_out;
    u16t* wsK = (u16t*)d_ws;
    u16t* wsV = wsK + (size_t)Bb * Hh * NKT * TILE_ELEMS;
    preconv_kernel<<<dim3(Bb * Hh * NKT), dim3(256), 0, stream>>>(x, wsK, wsV);
    attn_kernel<<<dim3(NBLK), dim3(256), 0, stream>>>(x, tk, tv, wsK, wsV, out);
}

// Round 18
// 62.499 us; speedup vs baseline: 1.0408x; 1.0408x over previous
//
#include <hip/hip_runtime.h>
#include <hip/hip_bf16.h>

#define Bb 8
#define Nn 1024
#define Hh 12
#define C3 2304
#define KK_E 0.1803368801f   // (1/8) * log2(e)
#define NQB 128              // queries per block (4 waves x 32)
#define KVBLK 64
#define NT 29
#define NQT (Nn / NQB)       // 8
#define NKT (Nn / KVBLK)     // 16
#define NBLK (Bb * Hh * NQT) // 768
#define TILE_ELEMS 4096      // 64x64 bf16 tile

typedef short bf16x8 __attribute__((ext_vector_type(8)));
typedef float f32x16 __attribute__((ext_vector_type(16)));
typedef unsigned v2u __attribute__((ext_vector_type(2)));
typedef unsigned short u16t;

__device__ __forceinline__ float b2f(u16t v) {
    union { unsigned u; float f; } x; x.u = ((unsigned)v) << 16; return x.f;
}
__device__ __forceinline__ u16t f2b(float f) {
    union { float f; unsigned u; } x; x.f = f;
    unsigned r = x.u + 0x7fffu + ((x.u >> 16) & 1u);
    return (u16t)(r >> 16);
}
// single-instruction packed f32->bf16 (T12): dst.lo=bf16(a), dst.hi=bf16(b)
__device__ __forceinline__ unsigned pk2a(float a, float b) {
    unsigned r;
    asm("v_cvt_pk_bf16_f32 %0, %1, %2" : "=v"(r) : "v"(a), "v"(b));
    return r;
}

// ---------------- pass 1: fp32 -> bf16 in FRAG-LINEAR tile layout ----------------
// K tile (8KB): u16 idx = (key&31)*8 + (key>>5)*256 + ((d>>3)&1)*512 + (d>>4)*1024 + (d&7)
// V tile (8KB): u16 idx = (d&31)*8 + ((d>>5)&1)*256 + ((key>>3)&1)*512 + (key>>4)*1024 + (key&7)
// -> every MFMA fragment is 64 consecutive 16B chunks (one coalesced dwordx4 per lane)
__global__ __launch_bounds__(256) void preconv_kernel(
        const float* __restrict__ x, u16t* __restrict__ wsK, u16t* __restrict__ wsV) {
    __shared__ __align__(16) u16t Vt[TILE_ELEMS];
    const int bid = blockIdx.x;                 // ((b*H + h)*NKT + kt)
    const int kt = bid % NKT;
    const int h  = (bid / NKT) % Hh;
    const int b  = bid / (NKT * Hh);
    const int tid = threadIdx.x;
    const float* xb = x + (size_t)b * Nn * C3 + (size_t)kt * KVBLK * C3 + 768 + h * 64;
    u16t* Kdst = wsK + (size_t)bid * TILE_ELEMS;
    u16t* Vdst = wsV + (size_t)bid * TILE_ELEMS;

    #pragma unroll
    for (int rep = 0; rep < 4; ++rep) {
        int idx = tid + rep * 256;
        int m = idx >> 4;               // key 0..63
        int d0 = (idx & 15) * 4;        // d0 in {0,4,...,60}
        const float* src = &xb[(size_t)m * C3 + d0];
        float4 k4 = *(const float4*)src;
        uint2 kp;
        kp.x = pk2a(k4.x, k4.y);
        kp.y = pk2a(k4.z, k4.w);
        int ko = (m & 31) * 8 + (m >> 5) * 256 + ((d0 >> 3) & 1) * 512
               + (d0 >> 4) * 1024 + (d0 & 7);
        *(uint2*)&Kdst[ko] = kp;        // direct global, 8B aligned
        float4 v4 = *(const float4*)(src + 768);
        int vb = ((m >> 3) & 1) * 512 + (m >> 4) * 1024 + (m & 7);
        Vt[((d0 + 0) & 31) * 8 + (((d0 + 0) >> 5) & 1) * 256 + vb] = f2b(v4.x);
        Vt[((d0 + 1) & 31) * 8 + (((d0 + 1) >> 5) & 1) * 256 + vb] = f2b(v4.y);
        Vt[((d0 + 2) & 31) * 8 + (((d0 + 2) >> 5) & 1) * 256 + vb] = f2b(v4.z);
        Vt[((d0 + 3) & 31) * 8 + (((d0 + 3) >> 5) & 1) * 256 + vb] = f2b(v4.w);
    }
    __syncthreads();
    // tile already frag-linear in LDS: plain linear copy-out
    const float4* s = (const float4*)Vt;
    float4* d = (float4*)Vdst;
    d[tid] = s[tid];
    d[tid + 256] = s[tid + 256];
}

// ---------------- pass 2: attention — zero barriers, K/V register-resident ------
// r13 final structure (62.5us, VGPR 84 clean, zero scratch; reproduced r16).
// out2 epilogue is a 32x64x29 GEMM done with 4 MFMAs into `of`.
// LDS: per-wave 4KB slab: wdiag bf16 [32][27] @0; qrel bf16 [32][29] @1792,
// reused after the loop as W[32][32] bf16 (the out2 B-operand).
// __launch_bounds__(256,3): budget 170 — the only clean budget for this body.
// CLOSED AXES (five experiments): occupancy>3waves/SIMD (r8-r11: ~132 unified
// regs/wave incl. accum -> any tighter cap = wholesale spill); ANY +16-reg ILP
// state, cross-step or transient (r12/r14/r15/r17 -> spill, WRITE_SIZE 33-52MB).
__global__ __launch_bounds__(256, 3) void attn_kernel(
        const float* __restrict__ x,
        const float* __restrict__ tk,
        const float* __restrict__ tv,
        const u16t* __restrict__ wsK,
        const u16t* __restrict__ wsV,
        float* __restrict__ out) {
    __shared__ __align__(16) char smem[16384];

    const int tid = threadIdx.x;
    const int work = (blockIdx.x & 7) * (NBLK / 8) + (blockIdx.x >> 3);
    const int qt = work % NQT;
    const int h  = (work / NQT) % Hh;
    const int b  = work / (NQT * Hh);
    const int lane = tid & 63;
    const int w = tid >> 6;
    const int lq = lane & 31;
    const int hi = lane >> 5;
    const int q0 = qt * NQB;
    const int qw0 = q0 + w * 32;

    char* slab   = smem + w * 4096;
    u16t* wdiagw = (u16t*)slab;              // [32][27] bf16
    u16t* qrelw  = (u16t*)(slab + 1792);     // [32][29] bf16 -> W[32][32] after loop

    const u16t* Kbase = wsK + (size_t)((b * Hh + h) * NKT) * TILE_ELEMS;
    const u16t* Vbase = wsV + (size_t)((b * Hh + h) * NKT) * TILE_ELEMS;
    const int lofs = lq * 8 + hi * 512;      // per-lane u16 offset inside a tile

    // ---- tile-0 K/V fragments straight into registers (coalesced dwordx4) ----
    bf16x8 kfr[2][4];   // [kb][slot]
    bf16x8 vfr[4][2];   // [kbj][db]
    {
        const u16t* Kt0 = Kbase + lofs;
        const u16t* Vt0 = Vbase + lofs;
        #pragma unroll
        for (int kb = 0; kb < 2; ++kb)
            #pragma unroll
            for (int slot = 0; slot < 4; ++slot)
                kfr[kb][slot] = *(const bf16x8*)&Kt0[kb * 256 + slot * 1024];
        #pragma unroll
        for (int kbj = 0; kbj < 4; ++kbj)
            #pragma unroll
            for (int db = 0; db < 2; ++db)
                vfr[kbj][db] = *(const bf16x8*)&Vt0[db * 256 + kbj * 1024];
    }

    // ---- Q fragments direct from global, pre-scaled by KK_E ----
    const float* xq = x + (size_t)b * Nn * C3 + (size_t)(qw0 + lq) * C3 + h * 64;
    bf16x8 qB[4];
    #pragma unroll
    for (int slot = 0; slot < 4; ++slot) {
        float4 a4 = *(const float4*)&xq[slot * 16 + hi * 8];
        float4 b4 = *(const float4*)&xq[slot * 16 + hi * 8 + 4];
        union { bf16x8 v; unsigned u[4]; } pk;
        pk.u[0] = pk2a(a4.x * KK_E, a4.y * KK_E);
        pk.u[1] = pk2a(a4.z * KK_E, a4.w * KK_E);
        pk.u[2] = pk2a(b4.x * KK_E, b4.y * KK_E);
        pk.u[3] = pk2a(b4.z * KK_E, b4.w * KK_E);
        qB[slot] = pk.v;
    }

    // ---- qrel[q][t] = (KK_E*Q[q,:]).tk[t,:] via 4 MFMAs: D[q=crow(reg,hi)][t=lq] ----
    {
        const int tc = lq > 28 ? 28 : lq;
        f32x16 qr = {};
        #pragma unroll
        for (int slot = 0; slot < 4; ++slot) {
            const float* tp = &tk[tc * 64 + slot * 16 + hi * 8];
            float4 a4 = *(const float4*)tp;
            float4 b4 = *(const float4*)(tp + 4);
            union { bf16x8 v; unsigned u[4]; } pk;
            pk.u[0] = pk2a(a4.x, a4.y); pk.u[1] = pk2a(a4.z, a4.w);
            pk.u[2] = pk2a(b4.x, b4.y); pk.u[3] = pk2a(b4.z, b4.w);
            qr = __builtin_amdgcn_mfma_f32_32x32x16_bf16(qB[slot], pk.v, qr, 0, 0, 0);
        }
        if (lq <= 28) {
            #pragma unroll
            for (int reg = 0; reg < 16; ++reg) {
                int qrow = (reg & 3) + 8 * (reg >> 2) + 4 * hi;
                qrelw[qrow * NT + lq] = f2b(qr[reg]);
            }
        }
    }
    // zero wdiag (wave-private; compiler orders LDS ops within the wave)
    for (int i = lane; i < 432; i += 64) ((unsigned*)wdiagw)[i] = 0u;

    const float qb0  = b2f(qrelw[lq * NT + 0]);    // already scaled
    const float qb28 = b2f(qrelw[lq * NT + 28]);

    f32x16 of[2] = {};
    float lowA = 0.f, highA = 0.f;

    for (int kt = 0; kt < NKT; ++kt) {
        const int key00 = kt * KVBLK;
        const bool more = (kt + 1 < NKT);
        const u16t* Ktn = Kbase + (size_t)(kt + 1) * TILE_ELEMS + lofs;
        const u16t* Vtn = Vbase + (size_t)(kt + 1) * TILE_ELEMS + lofs;

        #pragma unroll
        for (int kb = 0; kb < 2; ++kb) {
            const int kbase = key00 + kb * 32;
            const bool flo = (kbase + 31 - qw0 <= -14);
            const bool fhi = (kbase - (qw0 + 31) >= 14);
            const float binit = flo ? qb0 : (fhi ? qb28 : 0.f);
            f32x16 s;
            #pragma unroll
            for (int r = 0; r < 16; ++r) s[r] = binit;   // bias folded into C-init
            __builtin_amdgcn_s_setprio(1);
            #pragma unroll
            for (int slot = 0; slot < 4; ++slot)
                s = __builtin_amdgcn_mfma_f32_32x32x16_bf16(kfr[kb][slot], qB[slot], s, 0, 0, 0);
            __builtin_amdgcn_s_setprio(0);
            // phase-shifted reload: K(kt+1) for this kb, right after last use
            if (more) {
                #pragma unroll
                for (int slot = 0; slot < 4; ++slot)
                    kfr[kb][slot] = *(const bf16x8*)&Ktn[kb * 256 + slot * 1024];
            }
            // lane holds S^T[key = kbase+(r&3)+8*(r>>2)+4*hi][q = qw0+lq] (+bias)
            float e[16];
            if (flo || fhi) {
                #pragma unroll
                for (int r = 0; r < 16; ++r) e[r] = __builtin_amdgcn_exp2f(s[r]);
                float a0 = (e[0]+e[1]) + (e[2]+e[3]);
                float a1 = (e[4]+e[5]) + (e[6]+e[7]);
                float a2 = (e[8]+e[9]) + (e[10]+e[11]);
                float a3 = (e[12]+e[13]) + (e[14]+e[15]);
                float at = (a0+a1) + (a2+a3);
                if (flo) lowA += at; else highA += at;
            } else {
                const int qg = qw0 + lq;
                #pragma unroll
                for (int r = 0; r < 16; ++r) {
                    int key = kbase + (r & 3) + 8 * (r >> 2) + 4 * hi;
                    int delta = key - qg;
                    int t = delta + 14;
                    t = t < 0 ? 0 : (t > 28 ? 28 : t);
                    e[r] = __builtin_amdgcn_exp2f(s[r] + b2f(qrelw[lq * NT + t]));
                    if (delta <= -14)      lowA += e[r];
                    else if (delta >= 14)  highA += e[r];
                    else                   wdiagw[lq * 27 + delta + 13] = f2b(e[r]);
                }
            }
            // T12: cvt_pk + permlane32_swap -> PV B-frags in registers
            unsigned A0 = pk2a(e[0],  e[1]),  B0 = pk2a(e[2],  e[3]);
            unsigned C0 = pk2a(e[4],  e[5]),  D0 = pk2a(e[6],  e[7]);
            unsigned A1 = pk2a(e[8],  e[9]),  B1 = pk2a(e[10], e[11]);
            unsigned C1 = pk2a(e[12], e[13]), D1 = pk2a(e[14], e[15]);
            v2u r0 = __builtin_amdgcn_permlane32_swap(A0, C0, false, false);
            v2u r1 = __builtin_amdgcn_permlane32_swap(B0, D0, false, false);
            v2u r2 = __builtin_amdgcn_permlane32_swap(A1, C1, false, false);
            v2u r3 = __builtin_amdgcn_permlane32_swap(B1, D1, false, false);
            union { bf16x8 v; unsigned u[4]; } pf0, pf1;
            pf0.u[0] = r0[0]; pf0.u[1] = r1[0]; pf0.u[2] = r0[1]; pf0.u[3] = r1[1];
            pf1.u[0] = r2[0]; pf1.u[1] = r3[0]; pf1.u[2] = r2[1]; pf1.u[3] = r3[1];
            __builtin_amdgcn_s_setprio(1);
            #pragma unroll
            for (int db = 0; db < 2; ++db) {
                of[db] = __builtin_amdgcn_mfma_f32_32x32x16_bf16(vfr[kb*2+0][db], pf0.v, of[db], 0, 0, 0);
                of[db] = __builtin_amdgcn_mfma_f32_32x32x16_bf16(vfr[kb*2+1][db], pf1.v, of[db], 0, 0, 0);
            }
            __builtin_amdgcn_s_setprio(0);
            // phase-shifted reload: V(kt+1) for this kb's two key sub-groups
            if (more) {
                #pragma unroll
                for (int j = 0; j < 2; ++j)
                    #pragma unroll
                    for (int db = 0; db < 2; ++db)
                        vfr[kb*2+j][db] = *(const bf16x8*)&Vtn[db * 256 + (kb*2+j) * 1024];
            }
        }
    }

    // ---- per-lane finish: both hi halves get full row sums via one swap ----
    lowA  += __shfl_xor(lowA, 32, 64);
    highA += __shfl_xor(highA, 32, 64);
    float wsum = lowA + highA;
    #pragma unroll
    for (int t = 1; t <= 27; ++t) wsum += b2f(wdiagw[lq * 27 + t - 1]);

    // ---- out2 as a 32x64x29 GEMM: W[q][t] @ tv[t][d], 4 MFMAs into `of` ----
    // W[32][32] bf16 built in the dead qrel slab: [lowA | wdiag(27) | highA | 0,0,0]
    {
        u16t* Wl = qrelw;
        union { u16t s[8]; uint4 v; } h0, h1;
        if (hi == 0) {                       // t = 0..15
            h0.s[0] = f2b(lowA);
            #pragma unroll
            for (int t = 1; t <= 7; ++t)  h0.s[t] = wdiagw[lq * 27 + t - 1];
            #pragma unroll
            for (int t = 8; t <= 15; ++t) h1.s[t - 8] = wdiagw[lq * 27 + t - 1];
        } else {                             // t = 16..31
            #pragma unroll
            for (int t = 16; t <= 23; ++t) h0.s[t - 16] = wdiagw[lq * 27 + t - 1];
            #pragma unroll
            for (int t = 24; t <= 27; ++t) h1.s[t - 24] = wdiagw[lq * 27 + t - 1];
            h1.s[4] = f2b(highA);            // t = 28
            h1.s[5] = 0; h1.s[6] = 0; h1.s[7] = 0;
        }
        *(uint4*)&Wl[lq * 32 + hi * 16]     = h0.v;
        *(uint4*)&Wl[lq * 32 + hi * 16 + 8] = h1.v;
        // B-operand frags (same layout as qB): lane -> W[q=lq][t = slot*16 + hi*8 + j]
        bf16x8 wb0 = *(const bf16x8*)&Wl[lq * 32 + hi * 8];
        bf16x8 wb1 = *(const bf16x8*)&Wl[lq * 32 + 16 + hi * 8];
        // A-operand frags: A[d=lq (+32*dh)][t] = tv[t][d]; t>28 zero-padded
        #pragma unroll
        for (int dh = 0; dh < 2; ++dh) {
            union { bf16x8 v; unsigned u[4]; } a0, a1;
            #pragma unroll
            for (int jj = 0; jj < 4; ++jj) {
                int t0 = hi * 8 + 2 * jj;
                a0.u[jj] = pk2a(tv[t0 * 64 + lq + 32 * dh],
                                tv[(t0 + 1) * 64 + lq + 32 * dh]);
                int t1 = 16 + hi * 8 + 2 * jj;
                float v0 = (t1     <= 28) ? tv[t1 * 64 + lq + 32 * dh]       : 0.f;
                float v1 = (t1 + 1 <= 28) ? tv[(t1 + 1) * 64 + lq + 32 * dh] : 0.f;
                a1.u[jj] = pk2a(v0, v1);
            }
            of[dh] = __builtin_amdgcn_mfma_f32_32x32x16_bf16(a0.v, wb0, of[dh], 0, 0, 0);
            of[dh] = __builtin_amdgcn_mfma_f32_32x32x16_bf16(a1.v, wb1, of[dh], 0, 0, 0);
        }
    }
    const float linv = __builtin_amdgcn_rcpf(wsum);

    // ---- epilogue: out[q][d] = of[d][q] / L[q] (of = PV + rel-V) ----
    {
        float* orow = &out[((size_t)b * Nn + qw0 + lq) * 768 + h * 64];
        #pragma unroll
        for (int db = 0; db < 2; ++db)
            #pragma unroll
            for (int rq = 0; rq < 4; ++rq) {
                int d0 = db * 32 + rq * 8 + hi * 4;
                float4 o4;
                o4.x = of[db][rq * 4 + 0] * linv;
                o4.y = of[db][rq * 4 + 1] * linv;
                o4.z = of[db][rq * 4 + 2] * linv;
                o4.w = of[db][rq * 4 + 3] * linv;
                *(float4*)&orow[d0] = o4;
            }
    }
}

extern "C" void kernel_launch(void* const* d_in, const int* in_sizes, int n_in,
                              void* d_out, int out_size, void* d_ws, size_t ws_size,
                              hipStream_t stream) {
    const float* x  = (const float*)d_in[0];
    const float* tk = (const float*)d_in[1];
    const float* tv = (const float*)d_in[2];
    float* out = (float*)d_out;
    u16t* wsK = (u16t*)d_ws;
    u16t* wsV = wsK + (size_t)Bb * Hh * NKT * TILE_ELEMS;
    preconv_kernel<<<dim3(Bb * Hh * NKT), dim3(256), 0, stream>>>(x, wsK, wsV);
    attn_kernel<<<dim3(NBLK), dim3(256), 0, stream>>>(x, tk, tv, wsK, wsV, out);
}